// Round 1
// baseline (310.907 us; speedup 1.0000x reference)
//
#include <hip/hip_runtime.h>
#include <hip/hip_bf16.h>
#include <stdint.h>

typedef __bf16 bf16x8 __attribute__((ext_vector_type(8)));
typedef float  f32x4  __attribute__((ext_vector_type(4)));
typedef __attribute__((address_space(1))) uint32_t u32_g;
typedef __attribute__((address_space(3))) uint32_t u32_l;
typedef unsigned short u16;

__device__ __forceinline__ void gload16(const void* g, void* l) {
    __builtin_amdgcn_global_load_lds((u32_g*)g, (u32_l*)l, 16, 0, 0);
}

// ---------------------------------------------------------------------------
// Kernel: prep — WT[z][vec] = bf16(w_out[vec][z]);  norm[i][j] = mask^T mask + 1e-3
// ---------------------------------------------------------------------------
__global__ __launch_bounds__(256) void k_prep(const float* __restrict__ w_out,
                                              const float* __restrict__ mask,
                                              u16* __restrict__ WT,
                                              float* __restrict__ normv) {
    int idx = blockIdx.x * 256 + threadIdx.x;
    if (blockIdx.x < 512) {
        // idx = n*1024 + k ;  WT[n][k] = w_out[k][n]
        int n = idx >> 10, k = idx & 1023;
        __bf16 v = (__bf16)w_out[k * 128 + n];
        WT[idx] = __builtin_bit_cast(u16, v);
    } else {
        int o = idx - 131072;            // 0..65535
        int i = o >> 8, j = o & 255;
        float acc = 1e-3f;
        for (int s = 0; s < 256; ++s)
            acc += mask[s * 256 + i] * mask[s * 256 + j];
        normv[o] = acc;
    }
}

// ---------------------------------------------------------------------------
// Kernel: LayerNorm + dual projection.  One block per (s,i) row.
// Writes AT[(i*32+h)*256 + s], BT[(i*32+h)*256 + s]  (bf16 bits)
// ---------------------------------------------------------------------------
__global__ __launch_bounds__(256) void k_lnproj(
        const float* __restrict__ M, const float* __restrict__ mask,
        const float* __restrict__ lnw, const float* __restrict__ lnb,
        const float* __restrict__ w1, const float* __restrict__ b1,
        const float* __restrict__ w2, const float* __restrict__ b2,
        u16* __restrict__ AT, u16* __restrict__ BT) {
    const int i = blockIdx.x, s = blockIdx.y, t = threadIdx.x;
    __shared__ float ln_lds[256];
    __shared__ float pa[8][32];
    __shared__ float pb[8][32];
    __shared__ float red[8];

    float x = M[((size_t)s * 256 + i) * 256 + t];
    float s1 = x, s2 = x * x;
#pragma unroll
    for (int o = 1; o < 64; o <<= 1) {
        s1 += __shfl_xor(s1, o);
        s2 += __shfl_xor(s2, o);
    }
    if ((t & 63) == 0) { red[(t >> 6) * 2] = s1; red[(t >> 6) * 2 + 1] = s2; }
    __syncthreads();
    float tot1 = red[0] + red[2] + red[4] + red[6];
    float tot2 = red[1] + red[3] + red[5] + red[7];
    float mu   = tot1 * 0.00390625f;
    float var  = tot2 * 0.00390625f - mu * mu;
    float rstd = rsqrtf(var + 1e-5f);
    float ln   = (x - mu) * rstd * lnw[t] + lnb[t];
    ln_lds[t] = ln;
    __syncthreads();

    // 8 segments x 32 h; segment takes c = cc*8 + seg (bank-conflict-free)
    const int h = t & 31, seg = t >> 5;
    float aacc = 0.f, bacc = 0.f;
#pragma unroll
    for (int cc = 0; cc < 32; ++cc) {
        int c = cc * 8 + seg;
        float l = ln_lds[c];
        aacc += l * w1[c * 32 + h];
        bacc += l * w2[c * 32 + h];
    }
    pa[seg][h] = aacc;
    pb[seg][h] = bacc;
    __syncthreads();
    if (t < 64) {
        int hh = t & 31;
        float mk = mask[(size_t)s * 256 + i];
        if (t < 32) {
            float a = b1[hh];
#pragma unroll
            for (int g = 0; g < 8; ++g) a += pa[g][hh];
            a *= mk;
            __bf16 v = (__bf16)a;
            AT[((size_t)i * 32 + hh) * 256 + s] = __builtin_bit_cast(u16, v);
        } else {
            float b = b2[hh];
#pragma unroll
            for (int g = 0; g < 8; ++g) b += pb[g][hh];
            b *= mk;
            __bf16 v = (__bf16)b;
            BT[((size_t)i * 32 + hh) * 256 + s] = __builtin_bit_cast(u16, v);
        }
    }
}

// ---------------------------------------------------------------------------
// Kernel: fused outer-product GEMM1 (128x128x256) + w_out GEMM2 + epilogue
// grid (64,64): block (bx,by) handles i in [bx*4, bx*4+4), j in [by*4, by*4+4)
// LDS: two 32KB buffers {A[128][64], B[128][64]} bf16, XOR-swizzled; P reuses buf0.
// ---------------------------------------------------------------------------
__global__ __launch_bounds__(256) void k_fused(
        const u16* __restrict__ AT, const u16* __restrict__ BT,
        const u16* __restrict__ WT, const float* __restrict__ normv,
        const float* __restrict__ b_out, float* __restrict__ out) {
    __shared__ __align__(16) u16 sh[32768];   // 64 KB
    const int tid  = threadIdx.x;
    const int lane = tid & 63;
    const int wid  = tid >> 6;
    const int wr   = wid >> 1, wc = wid & 1;
    const int bx = blockIdx.x, by = blockIdx.y;
    const int m0 = bx * 128, n0g = by * 128;

    f32x4 acc[4][4] = {};

    auto stage = [&](int kt, int bufsel) {
        const int k0 = kt * 64;
        const size_t bb = (size_t)bufsel * 32768;   // byte offset of buffer
#pragma unroll
        for (int ii = 0; ii < 4; ++ii) {
            int flat = ii * 256 + tid;
            int r = flat >> 3, slot = flat & 7;
            int gs = slot ^ (r & 7);                // pre-swizzled source column
            const char* src = (const char*)AT + (((size_t)(m0 + r)) * 256 + k0) * 2 + gs * 16;
            char* dst = (char*)sh + bb + (size_t)(ii * 256 + (tid & ~63)) * 16;
            gload16(src, dst);
        }
#pragma unroll
        for (int ii = 0; ii < 4; ++ii) {
            int flat = ii * 256 + tid;
            int r = flat >> 3, slot = flat & 7;
            int gs = slot ^ (r & 7);
            const char* src = (const char*)BT + (((size_t)(n0g + r)) * 256 + k0) * 2 + gs * 16;
            char* dst = (char*)sh + bb + 16384 + (size_t)(ii * 256 + (tid & ~63)) * 16;
            gload16(src, dst);
        }
    };

    auto compute = [&](int bufsel) {
        const char* Ab = (const char*)sh + (size_t)bufsel * 32768;
        const char* Bb = Ab + 16384;
#pragma unroll
        for (int ks = 0; ks < 2; ++ks) {
            bf16x8 af[4], bfr[4];
#pragma unroll
            for (int f = 0; f < 4; ++f) {
                int row = wr * 64 + f * 16 + (lane & 15);
                int kb  = ks * 64 + ((lane >> 4) << 4);
                af[f] = *(const bf16x8*)(Ab + row * 128 + (kb ^ ((row & 7) << 4)));
            }
#pragma unroll
            for (int f = 0; f < 4; ++f) {
                int row = wc * 64 + f * 16 + (lane & 15);
                int kb  = ks * 64 + ((lane >> 4) << 4);
                bfr[f] = *(const bf16x8*)(Bb + row * 128 + (kb ^ ((row & 7) << 4)));
            }
#pragma unroll
            for (int i = 0; i < 4; ++i)
#pragma unroll
                for (int j = 0; j < 4; ++j)
                    acc[i][j] = __builtin_amdgcn_mfma_f32_16x16x32_bf16(af[i], bfr[j], acc[i][j], 0, 0, 0);
        }
    };

    stage(0, 0);
#pragma unroll
    for (int kt = 0; kt < 4; ++kt) {
        __syncthreads();                       // drains global_load_lds for tile kt
        if (kt < 3) stage(kt + 1, (kt + 1) & 1);
        compute(kt & 1);
    }

    // ---- write outer tile into P_lds[16][1024] bf16 (bytes [0,32768), swizzled)
    // last compute used buf1 (bytes 32768..), so no barrier needed before this.
#pragma unroll
    for (int i = 0; i < 4; ++i)
#pragma unroll
        for (int j = 0; j < 4; ++j)
#pragma unroll
            for (int r = 0; r < 4; ++r) {
                int mloc = wr * 64 + i * 16 + ((lane >> 4) << 2) + r;
                int nloc = wc * 64 + j * 16 + (lane & 15);
                int p    = ((mloc >> 5) << 2) | (nloc >> 5);
                int vec  = ((mloc & 31) << 5) | (nloc & 31);
                int byte = p * 2048 + vec * 2;
                byte ^= (p & 7) << 4;
                __bf16 v = (__bf16)acc[i][j][r];
                *(u16*)((char*)sh + byte) = __builtin_bit_cast(u16, v);
            }
    __syncthreads();

    // ---- GEMM2: [16 pairs x 1024] @ WT^T -> [16 x 128]; wave handles 32 z-cols
    f32x4 acc2[2] = {};
    const int zbase = wid * 32;
    for (int ks = 0; ks < 32; ++ks) {
        int k0 = ks * 32;
        int prow  = lane & 15;
        int byteA = prow * 2048 + (k0 + ((lane >> 4) << 3)) * 2;
        byteA ^= (prow & 7) << 4;
        bf16x8 af = *(const bf16x8*)((const char*)sh + byteA);
#pragma unroll
        for (int f = 0; f < 2; ++f) {
            int z = zbase + f * 16 + (lane & 15);
            bf16x8 bfr = *(const bf16x8*)((const char*)WT +
                          ((size_t)z * 1024 + k0 + ((lane >> 4) << 3)) * 2);
            acc2[f] = __builtin_amdgcn_mfma_f32_16x16x32_bf16(af, bfr, acc2[f], 0, 0, 0);
        }
    }

    // ---- epilogue: + b_out, / norm, store f32
    const int i0 = bx * 4, j0 = by * 4;
#pragma unroll
    for (int f = 0; f < 2; ++f)
#pragma unroll
        for (int r = 0; r < 4; ++r) {
            int p = ((lane >> 4) << 2) + r;
            int z = zbase + f * 16 + (lane & 15);
            int i = i0 + (p >> 2), j = j0 + (p & 3);
            float val = (acc2[f][r] + b_out[z]) / normv[i * 256 + j];
            out[(((size_t)i * 256) + j) * 128 + z] = val;
        }
}

// ---------------------------------------------------------------------------
extern "C" void kernel_launch(void* const* d_in, const int* in_sizes, int n_in,
                              void* d_out, int out_size, void* d_ws, size_t ws_size,
                              hipStream_t stream) {
    const float* M    = (const float*)d_in[0];
    const float* mask = (const float*)d_in[1];
    const float* lnw  = (const float*)d_in[2];
    const float* lnb  = (const float*)d_in[3];
    const float* w1   = (const float*)d_in[4];
    const float* b1   = (const float*)d_in[5];
    const float* w2   = (const float*)d_in[6];
    const float* b2   = (const float*)d_in[7];
    const float* wout = (const float*)d_in[8];
    const float* bout = (const float*)d_in[9];
    float* out = (float*)d_out;

    char* ws = (char*)d_ws;
    u16*   AT    = (u16*)(ws);                 // [8192][256] bf16 = 4 MB
    u16*   BT    = (u16*)(ws + 4194304);       // 4 MB
    u16*   WT    = (u16*)(ws + 8388608);       // [128][1024] bf16 = 256 KB
    float* normv = (float*)(ws + 8650752);     // [256][256] f32 = 256 KB

    k_prep  <<<768, 256, 0, stream>>>(wout, mask, WT, normv);
    k_lnproj<<<dim3(256, 256), 256, 0, stream>>>(M, mask, lnw, lnb, w1, b1, w2, b2, AT, BT);
    k_fused <<<dim3(64, 64), 256, 0, stream>>>(AT, BT, WT, normv, bout, out);
}

// Round 2
// 173.531 us; speedup vs baseline: 1.7917x; 1.7917x over previous
//
#include <hip/hip_runtime.h>
#include <hip/hip_bf16.h>
#include <stdint.h>

typedef __bf16 bf16x8 __attribute__((ext_vector_type(8)));
typedef float  f32x4  __attribute__((ext_vector_type(4)));
typedef __attribute__((address_space(1))) uint32_t u32_g;
typedef __attribute__((address_space(3))) uint32_t u32_l;
typedef unsigned short u16;
typedef u16 u16x4 __attribute__((ext_vector_type(4)));

__device__ __forceinline__ void gload16(const void* g, void* l) {
    __builtin_amdgcn_global_load_lds((u32_g*)g, (u32_l*)l, 16, 0, 0);
}

__device__ __forceinline__ u16 bf16bits(float v) {
    __bf16 h = (__bf16)v;
    return __builtin_bit_cast(u16, h);
}

// ---------------------------------------------------------------------------
// k_prep:
//   b <  512 : WT[n][k] = bf16(w_out[k][n])            (GEMM2 B operand)
//   b <  576 : WcatT[n][k] = bf16(n<32 ? w1[k][n] : w2[k][n-32])
//   else     : norm[i][j] = mask^T mask + 1e-3, one block per i
// ---------------------------------------------------------------------------
__global__ __launch_bounds__(256) void k_prep(const float* __restrict__ w_out,
                                              const float* __restrict__ mask,
                                              const float* __restrict__ w1,
                                              const float* __restrict__ w2,
                                              u16* __restrict__ WT,
                                              u16* __restrict__ WcatT,
                                              float* __restrict__ normv) {
    __shared__ float mcol[256];
    const int b = blockIdx.x, t = threadIdx.x;
    if (b < 512) {
        int idx = b * 256 + t;
        int n = idx >> 10, k = idx & 1023;
        WT[idx] = bf16bits(w_out[k * 128 + n]);
    } else if (b < 576) {
        int idx = (b - 512) * 256 + t;
        int n = idx >> 8, k = idx & 255;
        float v = (n < 32) ? w1[k * 32 + n] : w2[k * 32 + (n - 32)];
        WcatT[idx] = bf16bits(v);
    } else {
        int i = b - 576;
        mcol[t] = mask[(size_t)t * 256 + i];
        __syncthreads();
        float acc = 1e-3f;
#pragma unroll 8
        for (int s = 0; s < 256; ++s)
            acc += mcol[s] * mask[(size_t)s * 256 + t];
        normv[i * 256 + t] = acc;
    }
}

// ---------------------------------------------------------------------------
// k_lnproj: LayerNorm + dual projection via MFMA.
// Block = 64 rows (i fixed, s in [s0,s0+64)), 4 waves, 16 rows/wave.
// LDS: ln[64][256] bf16 swizzled @byte 0 (32KB), WcatT copy @byte 32768 (32KB).
// Output AT[(i*32+h)*256+s] / BT[...] bf16 bits, 8B stores (4 consecutive s).
// ---------------------------------------------------------------------------
__global__ __launch_bounds__(256, 2) void k_lnproj(
        const float* __restrict__ M, const float* __restrict__ mask,
        const float* __restrict__ lnw, const float* __restrict__ lnb,
        const float* __restrict__ b1, const float* __restrict__ b2,
        const u16* __restrict__ WcatT,
        u16* __restrict__ AT, u16* __restrict__ BT) {
    __shared__ __align__(16) u16 sh[32768];   // 64 KB
    const int tid = threadIdx.x, lane = tid & 63, w = tid >> 6;
    const int i = blockIdx.x, s0 = blockIdx.y * 64;

    // stage WcatT[64][256] bf16 -> LDS bytes [32768,65536), linear dest,
    // pre-swizzled global source (reader applies byte ^= (row&7)<<4)
#pragma unroll
    for (int p = 0; p < 8; ++p) {
        int flat = p * 256 + tid;               // 16B-chunk id, 0..2047
        int r = flat >> 5, slot = flat & 31;    // row, 16B slot in row
        int gs = slot ^ (r & 7);
        const char* src = (const char*)WcatT + (size_t)r * 512 + (size_t)gs * 16;
        char* dst = (char*)sh + 32768 + (size_t)flat * 16;
        gload16(src, dst);
    }

    // per-wave LN of rows w*16 .. w*16+15  (row -> s = s0 + row)
    float4 wv = *(const float4*)(lnw + lane * 4);
    float4 bv = *(const float4*)(lnb + lane * 4);
    float4 xv[16];
#pragma unroll
    for (int it = 0; it < 16; ++it) {
        int s = s0 + w * 16 + it;
        xv[it] = *(const float4*)(M + ((size_t)s * 256 + i) * 256 + lane * 4);
    }
#pragma unroll
    for (int it = 0; it < 16; ++it) {
        int row = w * 16 + it;
        float4 x = xv[it];
        float s1 = x.x + x.y + x.z + x.w;
        float s2 = x.x * x.x + x.y * x.y + x.z * x.z + x.w * x.w;
#pragma unroll
        for (int o = 1; o < 64; o <<= 1) {
            s1 += __shfl_xor(s1, o);
            s2 += __shfl_xor(s2, o);
        }
        float mu   = s1 * 0.00390625f;
        float var  = s2 * 0.00390625f - mu * mu;
        float rstd = rsqrtf(var + 1e-5f);
        u16x4 pk;
        pk[0] = bf16bits((x.x - mu) * rstd * wv.x + bv.x);
        pk[1] = bf16bits((x.y - mu) * rstd * wv.y + bv.y);
        pk[2] = bf16bits((x.z - mu) * rstd * wv.z + bv.z);
        pk[3] = bf16bits((x.w - mu) * rstd * wv.w + bv.w);
        int byte = (row * 512 + lane * 8) ^ ((row & 7) << 4);
        *(u16x4*)((char*)sh + byte) = pk;
    }
    __syncthreads();   // WcatT staging complete (LN rows are wave-local)

    // MFMA: [16 rows x 256] @ WcatT^T[64 x 256] -> [16 x 64] per wave
    f32x4 acc[4] = {};
#pragma unroll
    for (int kk = 0; kk < 8; ++kk) {
        int kb = kk * 64 + ((lane >> 4) << 4);     // byte offset of k within row
        int arow = w * 16 + (lane & 15);
        bf16x8 af = *(const bf16x8*)((const char*)sh +
                     ((arow * 512 + kb) ^ ((arow & 7) << 4)));
#pragma unroll
        for (int f = 0; f < 4; ++f) {
            int nrow = f * 16 + (lane & 15);
            bf16x8 bfr = *(const bf16x8*)((const char*)sh + 32768 +
                          ((nrow * 512 + kb) ^ ((nrow & 7) << 4)));
            acc[f] = __builtin_amdgcn_mfma_f32_16x16x32_bf16(af, bfr, acc[f], 0, 0, 0);
        }
    }

    // epilogue: +bias, *mask, pack 4 consecutive s as one 8B store
    const int sb = s0 + w * 16 + ((lane >> 4) << 2);
    float mk[4];
#pragma unroll
    for (int r = 0; r < 4; ++r) mk[r] = mask[(size_t)(sb + r) * 256 + i];
#pragma unroll
    for (int f = 0; f < 4; ++f) {
        int col = f * 16 + (lane & 15);            // 0..63
        float bias = (col < 32) ? b1[col] : b2[col - 32];
        u16* dst = ((col < 32) ? AT : BT) + ((size_t)i * 32 + (col & 31)) * 256 + sb;
        u16x4 pk;
#pragma unroll
        for (int r = 0; r < 4; ++r)
            pk[r] = bf16bits((acc[f][r] + bias) * mk[r]);
        *(u16x4*)dst = pk;
    }
}

// ---------------------------------------------------------------------------
// k_fused: outer-product GEMM1 (128x128x256) + w_out GEMM2 + epilogue
// grid (64,64): block (bx,by) handles i in [bx*4,bx*4+4), j in [by*4,by*4+4)
// ---------------------------------------------------------------------------
__global__ __launch_bounds__(256) void k_fused(
        const u16* __restrict__ AT, const u16* __restrict__ BT,
        const u16* __restrict__ WT, const float* __restrict__ normv,
        const float* __restrict__ b_out, float* __restrict__ out) {
    __shared__ __align__(16) u16 sh[32768];   // 64 KB
    const int tid  = threadIdx.x;
    const int lane = tid & 63;
    const int wid  = tid >> 6;
    const int wr   = wid >> 1, wc = wid & 1;
    const int bx = blockIdx.x, by = blockIdx.y;
    const int m0 = bx * 128, n0g = by * 128;

    f32x4 acc[4][4] = {};

    auto stage = [&](int kt, int bufsel) {
        const int k0 = kt * 64;
        const size_t bb = (size_t)bufsel * 32768;   // byte offset of buffer
#pragma unroll
        for (int ii = 0; ii < 4; ++ii) {
            int flat = ii * 256 + tid;
            int r = flat >> 3, slot = flat & 7;
            int gs = slot ^ (r & 7);
            const char* src = (const char*)AT + (((size_t)(m0 + r)) * 256 + k0) * 2 + gs * 16;
            char* dst = (char*)sh + bb + (size_t)(ii * 256 + (tid & ~63)) * 16;
            gload16(src, dst);
        }
#pragma unroll
        for (int ii = 0; ii < 4; ++ii) {
            int flat = ii * 256 + tid;
            int r = flat >> 3, slot = flat & 7;
            int gs = slot ^ (r & 7);
            const char* src = (const char*)BT + (((size_t)(n0g + r)) * 256 + k0) * 2 + gs * 16;
            char* dst = (char*)sh + bb + 16384 + (size_t)(ii * 256 + (tid & ~63)) * 16;
            gload16(src, dst);
        }
    };

    auto compute = [&](int bufsel) {
        const char* Ab = (const char*)sh + (size_t)bufsel * 32768;
        const char* Bb = Ab + 16384;
#pragma unroll
        for (int ks = 0; ks < 2; ++ks) {
            bf16x8 af[4], bfr[4];
#pragma unroll
            for (int f = 0; f < 4; ++f) {
                int row = wr * 64 + f * 16 + (lane & 15);
                int kb  = ks * 64 + ((lane >> 4) << 4);
                af[f] = *(const bf16x8*)(Ab + row * 128 + (kb ^ ((row & 7) << 4)));
            }
#pragma unroll
            for (int f = 0; f < 4; ++f) {
                int row = wc * 64 + f * 16 + (lane & 15);
                int kb  = ks * 64 + ((lane >> 4) << 4);
                bfr[f] = *(const bf16x8*)(Bb + row * 128 + (kb ^ ((row & 7) << 4)));
            }
#pragma unroll
            for (int i = 0; i < 4; ++i)
#pragma unroll
                for (int j = 0; j < 4; ++j)
                    acc[i][j] = __builtin_amdgcn_mfma_f32_16x16x32_bf16(af[i], bfr[j], acc[i][j], 0, 0, 0);
        }
    };

    stage(0, 0);
#pragma unroll
    for (int kt = 0; kt < 4; ++kt) {
        __syncthreads();                       // drains global_load_lds for tile kt
        if (kt < 3) stage(kt + 1, (kt + 1) & 1);
        compute(kt & 1);
    }

    // ---- write outer tile into P_lds[16][1024] bf16 (bytes [0,32768), swizzled)
#pragma unroll
    for (int i = 0; i < 4; ++i)
#pragma unroll
        for (int j = 0; j < 4; ++j)
#pragma unroll
            for (int r = 0; r < 4; ++r) {
                int mloc = wr * 64 + i * 16 + ((lane >> 4) << 2) + r;
                int nloc = wc * 64 + j * 16 + (lane & 15);
                int p    = ((mloc >> 5) << 2) | (nloc >> 5);
                int vec  = ((mloc & 31) << 5) | (nloc & 31);
                int byte = p * 2048 + vec * 2;
                byte ^= (p & 7) << 4;
                *(u16*)((char*)sh + byte) = bf16bits(acc[i][j][r]);
            }
    __syncthreads();

    // ---- GEMM2: [16 pairs x 1024] @ WT^T -> [16 x 128]; wave handles 32 z-cols
    f32x4 acc2[2] = {};
    const int zbase = wid * 32;
    for (int ks = 0; ks < 32; ++ks) {
        int k0 = ks * 32;
        int prow  = lane & 15;
        int byteA = prow * 2048 + (k0 + ((lane >> 4) << 3)) * 2;
        byteA ^= (prow & 7) << 4;
        bf16x8 af = *(const bf16x8*)((const char*)sh + byteA);
#pragma unroll
        for (int f = 0; f < 2; ++f) {
            int z = zbase + f * 16 + (lane & 15);
            bf16x8 bfr = *(const bf16x8*)((const char*)WT +
                          ((size_t)z * 1024 + k0 + ((lane >> 4) << 3)) * 2);
            acc2[f] = __builtin_amdgcn_mfma_f32_16x16x32_bf16(af, bfr, acc2[f], 0, 0, 0);
        }
    }

    // ---- epilogue: + b_out, / norm, store f32
    const int i0 = bx * 4, j0 = by * 4;
#pragma unroll
    for (int f = 0; f < 2; ++f)
#pragma unroll
        for (int r = 0; r < 4; ++r) {
            int p = ((lane >> 4) << 2) + r;
            int z = zbase + f * 16 + (lane & 15);
            int i = i0 + (p >> 2), j = j0 + (p & 3);
            float val = (acc2[f][r] + b_out[z]) / normv[i * 256 + j];
            out[(((size_t)i * 256) + j) * 128 + z] = val;
        }
}

// ---------------------------------------------------------------------------
extern "C" void kernel_launch(void* const* d_in, const int* in_sizes, int n_in,
                              void* d_out, int out_size, void* d_ws, size_t ws_size,
                              hipStream_t stream) {
    const float* M    = (const float*)d_in[0];
    const float* mask = (const float*)d_in[1];
    const float* lnw  = (const float*)d_in[2];
    const float* lnb  = (const float*)d_in[3];
    const float* w1   = (const float*)d_in[4];
    const float* b1   = (const float*)d_in[5];
    const float* w2   = (const float*)d_in[6];
    const float* b2   = (const float*)d_in[7];
    const float* wout = (const float*)d_in[8];
    const float* bout = (const float*)d_in[9];
    float* out = (float*)d_out;

    char* ws = (char*)d_ws;
    u16*   AT    = (u16*)(ws);                 // [8192][256] bf16 = 4 MB
    u16*   BT    = (u16*)(ws + 4194304);       // 4 MB
    u16*   WT    = (u16*)(ws + 8388608);       // [128][1024] bf16 = 256 KB
    float* normv = (float*)(ws + 8650752);     // [256][256] f32 = 256 KB
    u16*   WcatT = (u16*)(ws + 8912896);       // [64][256] bf16 = 32 KB

    k_prep  <<<832, 256, 0, stream>>>(wout, mask, w1, w2, WT, WcatT, normv);
    k_lnproj<<<dim3(256, 4), 256, 0, stream>>>(M, mask, lnw, lnb, b1, b2, WcatT, AT, BT);
    k_fused <<<dim3(64, 64), 256, 0, stream>>>(AT, BT, WT, normv, bout, out);
}

// Round 3
// 127.967 us; speedup vs baseline: 2.4296x; 1.3561x over previous
//
#include <hip/hip_runtime.h>
#include <hip/hip_bf16.h>
#include <stdint.h>

typedef __bf16 bf16x8 __attribute__((ext_vector_type(8)));
typedef float  f32x4  __attribute__((ext_vector_type(4)));
typedef __attribute__((address_space(1))) uint32_t u32_g;
typedef __attribute__((address_space(3))) uint32_t u32_l;
typedef unsigned short u16;
typedef u16 u16x4 __attribute__((ext_vector_type(4)));

__device__ __forceinline__ void gload16(const void* g, void* l) {
    __builtin_amdgcn_global_load_lds((u32_g*)g, (u32_l*)l, 16, 0, 0);
}

__device__ __forceinline__ u16 bf16bits(float v) {
    __bf16 h = (__bf16)v;
    return __builtin_bit_cast(u16, h);
}

// ---------------------------------------------------------------------------
// k_prep:
//   b <  512 : WT[z][kc'] = bf16(w_out[c*32+e][z]),  kc' = e*32 + c
//   b <  576 : WcatT[n][k] = bf16(n<32 ? w1[k][n] : w2[k][n-32])
//   else     : norm[i][j] = mask^T mask + 1e-3, one block per i
// ---------------------------------------------------------------------------
__global__ __launch_bounds__(256) void k_prep(const float* __restrict__ w_out,
                                              const float* __restrict__ mask,
                                              const float* __restrict__ w1,
                                              const float* __restrict__ w2,
                                              u16* __restrict__ WT,
                                              u16* __restrict__ WcatT,
                                              float* __restrict__ normv) {
    __shared__ float mcol[256];
    const int b = blockIdx.x, t = threadIdx.x;
    if (b < 512) {
        int idx = b * 256 + t;            // z*1024 + kc'
        int z = idx >> 10, kc = idx & 1023;
        int c = kc & 31, e = kc >> 5;
        WT[idx] = bf16bits(w_out[(c * 32 + e) * 128 + z]);
    } else if (b < 576) {
        int idx = (b - 512) * 256 + t;
        int n = idx >> 8, k = idx & 255;
        float v = (n < 32) ? w1[k * 32 + n] : w2[k * 32 + (n - 32)];
        WcatT[idx] = bf16bits(v);
    } else {
        int i = b - 576;
        mcol[t] = mask[(size_t)t * 256 + i];
        __syncthreads();
        float acc = 1e-3f;
#pragma unroll 8
        for (int s = 0; s < 256; ++s)
            acc += mcol[s] * mask[(size_t)s * 256 + t];
        normv[i * 256 + t] = acc;
    }
}

// ---------------------------------------------------------------------------
// k_lnproj: LayerNorm + dual projection via MFMA (unchanged from R2).
// ---------------------------------------------------------------------------
__global__ __launch_bounds__(256, 2) void k_lnproj(
        const float* __restrict__ M, const float* __restrict__ mask,
        const float* __restrict__ lnw, const float* __restrict__ lnb,
        const float* __restrict__ b1, const float* __restrict__ b2,
        const u16* __restrict__ WcatT,
        u16* __restrict__ AT, u16* __restrict__ BT) {
    __shared__ __align__(16) u16 sh[32768];   // 64 KB
    const int tid = threadIdx.x, lane = tid & 63, w = tid >> 6;
    const int i = blockIdx.x, s0 = blockIdx.y * 64;

#pragma unroll
    for (int p = 0; p < 8; ++p) {
        int flat = p * 256 + tid;
        int r = flat >> 5, slot = flat & 31;
        int gs = slot ^ (r & 7);
        const char* src = (const char*)WcatT + (size_t)r * 512 + (size_t)gs * 16;
        char* dst = (char*)sh + 32768 + (size_t)(p * 256 + (tid & ~63)) * 16;
        gload16(src, dst);
    }

    float4 wv = *(const float4*)(lnw + lane * 4);
    float4 bv = *(const float4*)(lnb + lane * 4);
    float4 xv[16];
#pragma unroll
    for (int it = 0; it < 16; ++it) {
        int s = s0 + w * 16 + it;
        xv[it] = *(const float4*)(M + ((size_t)s * 256 + i) * 256 + lane * 4);
    }
#pragma unroll
    for (int it = 0; it < 16; ++it) {
        int row = w * 16 + it;
        float4 x = xv[it];
        float s1 = x.x + x.y + x.z + x.w;
        float s2 = x.x * x.x + x.y * x.y + x.z * x.z + x.w * x.w;
#pragma unroll
        for (int o = 1; o < 64; o <<= 1) {
            s1 += __shfl_xor(s1, o);
            s2 += __shfl_xor(s2, o);
        }
        float mu   = s1 * 0.00390625f;
        float var  = s2 * 0.00390625f - mu * mu;
        float rstd = rsqrtf(var + 1e-5f);
        u16x4 pk;
        pk[0] = bf16bits((x.x - mu) * rstd * wv.x + bv.x);
        pk[1] = bf16bits((x.y - mu) * rstd * wv.y + bv.y);
        pk[2] = bf16bits((x.z - mu) * rstd * wv.z + bv.z);
        pk[3] = bf16bits((x.w - mu) * rstd * wv.w + bv.w);
        int byte = (row * 512 + lane * 8) ^ ((row & 7) << 4);
        *(u16x4*)((char*)sh + byte) = pk;
    }
    __syncthreads();

    f32x4 acc[4] = {};
#pragma unroll
    for (int kk = 0; kk < 8; ++kk) {
        int kb = kk * 64 + ((lane >> 4) << 4);
        int arow = w * 16 + (lane & 15);
        bf16x8 af = *(const bf16x8*)((const char*)sh +
                     ((arow * 512 + kb) ^ ((arow & 7) << 4)));
#pragma unroll
        for (int f = 0; f < 4; ++f) {
            int nrow = f * 16 + (lane & 15);
            bf16x8 bfr = *(const bf16x8*)((const char*)sh + 32768 +
                          ((nrow * 512 + kb) ^ ((nrow & 7) << 4)));
            acc[f] = __builtin_amdgcn_mfma_f32_16x16x32_bf16(af, bfr, acc[f], 0, 0, 0);
        }
    }

    const int sb = s0 + w * 16 + ((lane >> 4) << 2);
    float mk[4];
#pragma unroll
    for (int r = 0; r < 4; ++r) mk[r] = mask[(size_t)(sb + r) * 256 + i];
#pragma unroll
    for (int f = 0; f < 4; ++f) {
        int col = f * 16 + (lane & 15);
        float bias = (col < 32) ? b1[col] : b2[col - 32];
        u16* dst = ((col < 32) ? AT : BT) + ((size_t)i * 32 + (col & 31)) * 256 + sb;
        u16x4 pk;
#pragma unroll
        for (int r = 0; r < 4; ++r)
            pk[r] = bf16bits((acc[f][r] + bias) * mk[r]);
        *(u16x4*)dst = pk;
    }
}

// ---------------------------------------------------------------------------
// k_fused: 256x256x256 GEMM1 (8 waves, wave tile 128x64) + GEMM2 + epilogue.
// grid 1024: block handles i in [bx*8,bx*8+8), j in [by*8,by*8+8).
// LDS 128KB: dbuf {A[256][64],B[256][64]} bf16 swizzled; reused as P[64][1024].
// ---------------------------------------------------------------------------
__global__ __launch_bounds__(512, 2) void k_fused(
        const u16* __restrict__ AT, const u16* __restrict__ BT,
        const u16* __restrict__ WT, const float* __restrict__ normv,
        const float* __restrict__ b_out, float* __restrict__ out) {
    __shared__ __align__(16) u16 sh[65536];   // 128 KB
    const int tid  = threadIdx.x;
    const int lane = tid & 63;
    const int wid  = tid >> 6;
    const int wr   = wid >> 2, wc = wid & 3;   // 2 x 4 wave grid
    // XCD-bijective swizzle (nwg=1024, 8 XCDs, 128 blocks per XCD chunk)
    const int lid = blockIdx.x;
    const int swz = (lid & 7) * 128 + (lid >> 3);
    const int bx = swz & 31, by = swz >> 5;
    const int m0 = bx * 256, n0 = by * 256;

    f32x4 acc[8][4] = {};

    auto stage = [&](int kt, int bufsel) {
        const int k0 = kt * 64;
        const size_t bb = (size_t)bufsel * 65536;   // byte offset of buffer
#pragma unroll
        for (int ii = 0; ii < 4; ++ii) {
            int f = ii * 512 + tid;
            int r = f >> 3, slot = f & 7;
            int gs = slot ^ (r & 7);
            gload16((const char*)AT + (((size_t)(m0 + r)) * 256 + k0) * 2 + gs * 16,
                    (char*)sh + bb + (size_t)(ii * 512 + (tid & ~63)) * 16);
        }
#pragma unroll
        for (int ii = 0; ii < 4; ++ii) {
            int f = ii * 512 + tid;
            int r = f >> 3, slot = f & 7;
            int gs = slot ^ (r & 7);
            gload16((const char*)BT + (((size_t)(n0 + r)) * 256 + k0) * 2 + gs * 16,
                    (char*)sh + bb + 32768 + (size_t)(ii * 512 + (tid & ~63)) * 16);
        }
    };

    auto compute = [&](int bufsel) {
        const char* Ab = (const char*)sh + (size_t)bufsel * 65536;
        const char* Bb = Ab + 32768;
#pragma unroll
        for (int ks = 0; ks < 2; ++ks) {
            bf16x8 af[8], bfr[4];
            const int kb = ks * 64 + ((lane >> 4) << 4);
#pragma unroll
            for (int f = 0; f < 8; ++f) {
                int row = wr * 128 + f * 16 + (lane & 15);
                af[f] = *(const bf16x8*)(Ab + row * 128 + (kb ^ ((row & 7) << 4)));
            }
#pragma unroll
            for (int f = 0; f < 4; ++f) {
                int row = wc * 64 + f * 16 + (lane & 15);
                bfr[f] = *(const bf16x8*)(Bb + row * 128 + (kb ^ ((row & 7) << 4)));
            }
#pragma unroll
            for (int mi = 0; mi < 8; ++mi)
#pragma unroll
                for (int nj = 0; nj < 4; ++nj)
                    acc[mi][nj] = __builtin_amdgcn_mfma_f32_16x16x32_bf16(
                        af[mi], bfr[nj], acc[mi][nj], 0, 0, 0);
        }
    };

    stage(0, 0);
#pragma unroll
    for (int kt = 0; kt < 4; ++kt) {
        __syncthreads();                       // drains global_load_lds for tile kt
        if (kt < 3) stage(kt + 1, (kt + 1) & 1);
        compute(kt & 1);
    }
    __syncthreads();   // all computes done before P overwrites the buffers

    // ---- write outer tile into P[64 pairs][1024] bf16 (kc' = e*32+c), swizzled.
    // acc[mi][nj][r]: m = wr*128+mi*16+q*4+r (q=lane>>4), n = wc*64+nj*16+(lane&15)
    // pr = (m>>5)*8 + (n>>5); 4 r's are kc'-contiguous -> one 8B write.
#pragma unroll
    for (int mi = 0; mi < 8; ++mi)
#pragma unroll
        for (int nj = 0; nj < 4; ++nj) {
            int m = wr * 128 + mi * 16 + ((lane >> 4) << 2);
            int n = wc * 64 + nj * 16 + (lane & 15);
            int pr = ((m >> 5) << 3) | (n >> 5);
            int c0 = m & 31, e = n & 31;
            int byte = pr * 2048 + (e * 32 + c0) * 2;
            byte ^= ((pr ^ e) & 7) << 4;
            u16x4 pk;
#pragma unroll
            for (int r = 0; r < 4; ++r)
                pk[r] = bf16bits(acc[mi][nj][r]);
            *(u16x4*)((char*)sh + byte) = pk;
        }
    __syncthreads();

    // ---- GEMM2: [64 x 1024] @ WT^T[128 x 1024] -> [64 x 128]
    // wave (wr,wc): pairs [wr*32, wr*32+32), z in [wc*32, wc*32+32)
    f32x4 acc2[2][2] = {};
    const int prb = wr * 32 + (lane & 15);
    const int zb  = wc * 32 + (lane & 15);
    const int ko  = (lane >> 4) << 3;          // k offset (elements)
#pragma unroll 4
    for (int ks = 0; ks < 32; ++ks) {
        const int kc = ks * 32 + ko;
        bf16x8 pa[2], wb[2];
#pragma unroll
        for (int mf = 0; mf < 2; ++mf) {
            int pr = prb + mf * 16;
            int byte = pr * 2048 + kc * 2;
            byte ^= ((pr ^ ks) & 7) << 4;
            pa[mf] = *(const bf16x8*)((const char*)sh + byte);
        }
#pragma unroll
        for (int zf = 0; zf < 2; ++zf) {
            int z = zb + zf * 16;
            wb[zf] = *(const bf16x8*)(WT + (size_t)z * 1024 + kc);
        }
#pragma unroll
        for (int mf = 0; mf < 2; ++mf)
#pragma unroll
            for (int zf = 0; zf < 2; ++zf)
                acc2[mf][zf] = __builtin_amdgcn_mfma_f32_16x16x32_bf16(
                    pa[mf], wb[zf], acc2[mf][zf], 0, 0, 0);
    }

    // ---- epilogue: + b_out, / norm, store f32 (lanes 0-15 -> consecutive z)
    const int i0 = bx * 8, j0 = by * 8;
#pragma unroll
    for (int mf = 0; mf < 2; ++mf)
#pragma unroll
        for (int zf = 0; zf < 2; ++zf)
#pragma unroll
            for (int r = 0; r < 4; ++r) {
                int pr = wr * 32 + mf * 16 + ((lane >> 4) << 2) + r;
                int z  = wc * 32 + zf * 16 + (lane & 15);
                int i = i0 + (pr >> 3), j = j0 + (pr & 7);
                float val = (acc2[mf][zf][r] + b_out[z]) / normv[i * 256 + j];
                out[((size_t)(i * 256 + j)) * 128 + z] = val;
            }
}

// ---------------------------------------------------------------------------
extern "C" void kernel_launch(void* const* d_in, const int* in_sizes, int n_in,
                              void* d_out, int out_size, void* d_ws, size_t ws_size,
                              hipStream_t stream) {
    const float* M    = (const float*)d_in[0];
    const float* mask = (const float*)d_in[1];
    const float* lnw  = (const float*)d_in[2];
    const float* lnb  = (const float*)d_in[3];
    const float* w1   = (const float*)d_in[4];
    const float* b1   = (const float*)d_in[5];
    const float* w2   = (const float*)d_in[6];
    const float* b2   = (const float*)d_in[7];
    const float* wout = (const float*)d_in[8];
    const float* bout = (const float*)d_in[9];
    float* out = (float*)d_out;

    char* ws = (char*)d_ws;
    u16*   AT    = (u16*)(ws);                 // [8192][256] bf16 = 4 MB
    u16*   BT    = (u16*)(ws + 4194304);       // 4 MB
    u16*   WT    = (u16*)(ws + 8388608);       // [128][1024] bf16 = 256 KB
    float* normv = (float*)(ws + 8650752);     // [256][256] f32 = 256 KB
    u16*   WcatT = (u16*)(ws + 8912896);       // [64][256] bf16 = 32 KB

    k_prep  <<<832, 256, 0, stream>>>(wout, mask, w1, w2, WT, WcatT, normv);
    k_lnproj<<<dim3(256, 4), 256, 0, stream>>>(M, mask, lnw, lnb, b1, b2, WcatT, AT, BT);
    k_fused <<<1024, 512, 0, stream>>>(AT, BT, WT, normv, bout, out);
}